// Round 1
// baseline (239.933 us; speedup 1.0000x reference)
//
#include <hip/hip_runtime.h>
#include <math.h>

// ProbSparse attention (Informer). B=2 L=4096 H=8 D=64, U_part=u=45.
// R9: k_scoreM VALU cut to discriminate the L2-line-rate theory.
//  (a) threefry idx table hoisted to k_genidx (was recomputed 16x redundantly
//      across bh -> ~38% of scoreM VALU);
//  (b) 4-lane-per-query dot layout (64 q/block, lane owns an INTERLEAVED
//      16B-granule quarter-row so each load inst still covers 16 full 64B
//      lines; DPP reduce 4 steps -> 2). Per-sample wave cost 2.5 -> ~1.4 insts.
// L2 line traffic unchanged by construction. If scoreM lands ~38us the
// line-rate floor is confirmed (next: dedup/CSR restructure); if ~25us the
// VALU theory wins and scoreM is near done.
#define JAX_PARTITIONABLE 1

constexpr int Bc = 2, Lc = 4096, Hc = 8, Dc = 64;
constexpr int BHc = Bc * Hc;     // 16
constexpr int Uc = 45;           // top-k queries
constexpr int NSc = 45;          // samples per query

typedef float vfloat4 __attribute__((ext_vector_type(4)));

struct TF2 { unsigned a, b; };

__host__ __device__ constexpr unsigned rotl32(unsigned v, int n) {
  return (v << n) | (v >> (32 - n));
}

// Threefry-2x32, 20 rounds (JAX reference schedule).
__host__ __device__ constexpr TF2 tf2(unsigned k0, unsigned k1, unsigned x0, unsigned x1) {
  unsigned ks2 = k0 ^ k1 ^ 0x1BD11BDAu;
  x0 += k0; x1 += k1;
  x0 += x1; x1 = rotl32(x1, 13); x1 ^= x0;
  x0 += x1; x1 = rotl32(x1, 15); x1 ^= x0;
  x0 += x1; x1 = rotl32(x1, 26); x1 ^= x0;
  x0 += x1; x1 = rotl32(x1, 6);  x1 ^= x0;
  x0 += k1; x1 += ks2 + 1u;
  x0 += x1; x1 = rotl32(x1, 17); x1 ^= x0;
  x0 += x1; x1 = rotl32(x1, 29); x1 ^= x0;
  x0 += x1; x1 = rotl32(x1, 16); x1 ^= x0;
  x0 += x1; x1 = rotl32(x1, 24); x1 ^= x0;
  x0 += ks2; x1 += k0 + 2u;
  x0 += x1; x1 = rotl32(x1, 13); x1 ^= x0;
  x0 += x1; x1 = rotl32(x1, 15); x1 ^= x0;
  x0 += x1; x1 = rotl32(x1, 26); x1 ^= x0;
  x0 += x1; x1 = rotl32(x1, 6);  x1 ^= x0;
  x0 += k0; x1 += k1 + 3u;
  x0 += x1; x1 = rotl32(x1, 17); x1 ^= x0;
  x0 += x1; x1 = rotl32(x1, 29); x1 ^= x0;
  x0 += x1; x1 = rotl32(x1, 16); x1 ^= x0;
  x0 += x1; x1 = rotl32(x1, 24); x1 ^= x0;
  x0 += k1; x1 += ks2 + 4u;
  x0 += x1; x1 = rotl32(x1, 13); x1 ^= x0;
  x0 += x1; x1 = rotl32(x1, 15); x1 ^= x0;
  x0 += x1; x1 = rotl32(x1, 26); x1 ^= x0;
  x0 += x1; x1 = rotl32(x1, 6);  x1 ^= x0;
  x0 += ks2; x1 += k0 + 5u;
  return TF2{x0, x1};
}

// VALU-pipe partial-sum add via DPP (identity old=0 for invalid lanes).
template <int CTRL>
__device__ __forceinline__ float dpp_add(float x) {
  int t = __builtin_amdgcn_update_dpp(0, __float_as_int(x), CTRL, 0xF, 0xF, false);
  return x + __int_as_float(t);
}
// DPP-shifted value with own value as identity for invalid lanes (for max).
template <int CTRL>
__device__ __forceinline__ float dpp_idf(float x) {
  int t = __builtin_amdgcn_update_dpp(__float_as_int(x), __float_as_int(x), CTRL, 0xF, 0xF, false);
  return __int_as_float(t);
}
// Full-wave (64-lane) max/sum: result valid at lane 63, broadcast via readlane.
__device__ __forceinline__ float wave_max_bcast(float x) {
  x = fmaxf(x, dpp_idf<0x111>(x));   // row_shr:1
  x = fmaxf(x, dpp_idf<0x112>(x));   // row_shr:2
  x = fmaxf(x, dpp_idf<0x114>(x));   // row_shr:4
  x = fmaxf(x, dpp_idf<0x118>(x));   // row_shr:8  -> lane15 of each row = row max
  x = fmaxf(x, dpp_idf<0x142>(x));   // row_bcast:15
  x = fmaxf(x, dpp_idf<0x143>(x));   // row_bcast:31 -> lane63 = wave max
  return __int_as_float(__builtin_amdgcn_readlane(__float_as_int(x), 63));
}
__device__ __forceinline__ float wave_sum_bcast(float x) {
  x = dpp_add<0x111>(x);
  x = dpp_add<0x112>(x);
  x = dpp_add<0x114>(x);
  x = dpp_add<0x118>(x);
  x = dpp_add<0x142>(x);
  x = dpp_add<0x143>(x);
  return __int_as_float(__builtin_amdgcn_readlane(__float_as_int(x), 63));
}

// fmaf chain for a float4 dot accumulated into a: 4 VALU insts.
__device__ __forceinline__ float dot4_acc(float4 q, float4 k, float a) {
  a = fmaf(q.x, k.x, a);
  a = fmaf(q.y, k.y, a);
  a = fmaf(q.z, k.z, a);
  a = fmaf(q.w, k.w, a);
  return a;
}
__device__ __forceinline__ float dot4v(vfloat4 q, vfloat4 k, float a) {
  a = fmaf(q[0], k[0], a);
  a = fmaf(q[1], k[1], a);
  a = fmaf(q[2], k[2], a);
  a = fmaf(q[3], k[3], a);
  return a;
}

// Precompute the sample-index table once (bh-independent; was hashed 16x
// redundantly inside k_scoreM). g = q*45 + s, exact same counter mapping.
__global__ __launch_bounds__(256) void k_genidx(int* __restrict__ gidx) {
  unsigned g = blockIdx.x * 256u + threadIdx.x;   // 720*256 == 184320 exactly
  constexpr TF2 kb = tf2(0u, 1u, 0u, 1u);
  TF2 r = tf2(kb.a, kb.b, 0u, g);
  gidx[g] = (int)((r.a ^ r.b) & 4095u);
}

// M[bh][q] = max_s dot(Q[q],K[idx[q][s]]) - sum_s(...)/4096.
// 4 lanes per query, 64 queries per block (grid 16*64=1024; bh = bx&15 keeps
// the 2-bh-per-XCD L2 residency). Lane sec owns INTERLEAVED float4s
// {sec, sec+4, sec+8, sec+12} of the 256B row, so load inst j across the wave
// covers byte range [j*64, j*64+64) of 16 rows = 16 full 64B lines -> L2
// line-touch count identical to R8. DPP reduce: row_shr 1,2 -> lane sec==3.
__global__ __launch_bounds__(256) void k_scoreM(const float* __restrict__ Q, const float* __restrict__ K,
                                                const int* __restrict__ gidx, float* __restrict__ M) {
  __shared__ int sidx[64 * NSc];   // 2880
  int tid = threadIdx.x;
  int bx = blockIdx.x;
  int bh = bx & 15;
  int qblk = bx >> 4;              // 0..63
  int b = bh >> 3, h = bh & 7;
  int sec = tid & 3, qloc = tid >> 2;
  int q = qblk * 64 + qloc;
  {
    const int4* g4 = (const int4*)(gidx + qblk * (64 * NSc));
    int4* s4 = (int4*)sidx;
    for (int e = tid; e < 720; e += 256) s4[e] = g4[e];
  }
  __syncthreads();
  const vfloat4* Q4 = (const vfloat4*)Q;
  const vfloat4* K4 = (const vfloat4*)K;
  vfloat4 qr[4];
  int qb4 = ((b * Lc + q) * Hc + h) * 16 + sec;
  #pragma unroll
  for (int j = 0; j < 4; ++j) qr[j] = Q4[qb4 + 4 * j];
  int kbase = (b * Lc * Hc + h) * 16 + sec;
  const int* ip = sidx + qloc * NSc;
  float mx = -INFINITY, sm = 0.f;
  #pragma unroll
  for (int s0 = 0; s0 < NSc; s0 += 3) {     // 3-deep batch: 12 L2 loads in flight
    int kk[3];
    #pragma unroll
    for (int i = 0; i < 3; ++i) kk[i] = ip[s0 + i];
    vfloat4 kv[3][4];
    #pragma unroll
    for (int i = 0; i < 3; ++i) {
      #pragma unroll
      for (int j = 0; j < 4; ++j)
        kv[i][j] = __builtin_nontemporal_load(&K4[kbase + kk[i] * (Hc * 16) + 4 * j]);
    }
    #pragma unroll
    for (int i = 0; i < 3; ++i) {
      float a0 = dot4v(qr[0], kv[i][0], 0.f);
      a0 = dot4v(qr[1], kv[i][1], a0);
      float a1 = dot4v(qr[2], kv[i][2], 0.f);
      a1 = dot4v(qr[3], kv[i][3], a1);
      float p = a0 + a1;                     // lane partial (16 of 64 elems)
      p = dpp_add<0x111>(p);                 // quads are 4-aligned within DPP
      p = dpp_add<0x112>(p);                 // rows of 16 -> lane sec==3 = full dot
      mx = fmaxf(mx, p);                     // valid at sec==3; junk elsewhere
      sm += p;
    }
  }
  if (sec == 3) M[bh * Lc + q] = mx - sm * (1.0f / Lc);
}

// Radix-select top-45 of 4096 per bh (exact lax.top_k: value desc, index asc
// on ties). Then pre-gather the 45 selected Q rows into qg[bh][45][64].
__global__ __launch_bounds__(256) void k_topk(const float* __restrict__ M, const float* __restrict__ Q,
                                              int* __restrict__ topk, float* __restrict__ qg) {
  __shared__ unsigned su[Lc];      // 16 KB mapped keys
  __shared__ int hist[256];
  __shared__ int sfx[257];
  __shared__ unsigned s_prefix;
  __shared__ int s_r;
  __shared__ int n_gt, n_eq;
  __shared__ unsigned cu[64];
  __shared__ int cidx[64];
  __shared__ int eqi[64];
  __shared__ int srank[Uc];
  int bh = blockIdx.x, tid = threadIdx.x;
  int b = bh >> 3, h = bh & 7;
  const float* m = M + bh * Lc;
  for (int e = tid; e < Lc; e += 256) {
    unsigned bb = __float_as_uint(m[e]);
    su[e] = (bb & 0x80000000u) ? ~bb : (bb | 0x80000000u);
  }
  if (tid == 0) { s_r = Uc; s_prefix = 0u; n_gt = 0; n_eq = 0; }
  __syncthreads();
  #pragma unroll
  for (int p = 0; p < 4; ++p) {
    int shift = 24 - 8 * p;
    hist[tid] = 0;
    __syncthreads();
    unsigned pref = s_prefix;
    unsigned hmask = (p == 0) ? 0u : (0xFFFFFFFFu << (shift + 8));
    for (int e = tid; e < Lc; e += 256) {
      unsigned u = su[e];
      if ((u & hmask) == pref) atomicAdd(&hist[(u >> shift) & 255u], 1);
    }
    __syncthreads();
    sfx[tid] = hist[tid];
    __syncthreads();
    for (int off = 1; off < 256; off <<= 1) {   // inclusive suffix sum
      int v = (tid + off < 256) ? sfx[tid + off] : 0;
      __syncthreads();
      sfx[tid] += v;
      __syncthreads();
    }
    int r = s_r;
    __syncthreads();                            // all read s_r before update
    int above = (tid < 255) ? sfx[tid + 1] : 0;
    if (sfx[tid] >= r && above < r) {           // unique digit
      s_r = r - above;
      s_prefix = pref | ((unsigned)tid << shift);
    }
    __syncthreads();
  }
  unsigned T = s_prefix;                        // exact 45th-largest key
  int rf = s_r;                                 // #equals to take (>=1)
  for (int e = tid; e < Lc; e += 256) {
    unsigned u = su[e];
    if (u > T) {
      int p = atomicAdd(&n_gt, 1);              // <= 44
      cu[p] = u; cidx[p] = e;
    } else if (u == T) {
      int p = atomicAdd(&n_eq, 1);
      if (p < 64) eqi[p] = e;                   // >64-way ties: impossible for random-normal M
    }
  }
  __syncthreads();
  int ne = n_eq < 64 ? n_eq : 64;
  if (tid < ne) {
    int myi = eqi[tid];
    int rank = 0;
    for (int j = 0; j < ne; ++j) rank += (eqi[j] < myi);
    if (rank < rf) {
      int p = atomicAdd(&n_gt, 1);              // completes to exactly 45
      cu[p] = T; cidx[p] = myi;
    }
  }
  __syncthreads();
  if (tid < Uc) {
    unsigned mu = cu[tid]; int mi = cidx[tid];
    int rank = 0;
    for (int j = 0; j < Uc; ++j) {
      unsigned ju = cu[j]; int ji = cidx[j];
      rank += (ju > mu) || (ju == mu && ji < mi);
    }
    topk[bh * Uc + rank] = mi;
    srank[rank] = mi;
  }
  __syncthreads();
  const float4* Q4 = (const float4*)Q;
  float4* qg4 = (float4*)qg;
  for (int e = tid; e < Uc * 16; e += 256) {    // coalesced pre-gather of selected Q rows
    int t = e >> 4, dq = e & 15;
    qg4[bh * Uc * 16 + e] = Q4[((b * Lc + srank[t]) * Hc + h) * 16 + dq];
  }
}

// Flash-decoding partials: one block per (bh, CH-key chunk), CH = 4096/NC.
// NOTE: phase 2 assumes CH == 64 (one wave per score row); the NC=64 path is
// always taken in practice (ws_size >> 14 MB).
template<int NC>
__global__ __launch_bounds__(256) void k_attn(const float* __restrict__ qg, const float* __restrict__ K,
                                              const float* __restrict__ V, const int* __restrict__ amask,
                                              float* __restrict__ pO, float* __restrict__ pM,
                                              float* __restrict__ pL) {
  constexpr int CH = Lc / NC;
  constexpr int TG = 256 / CH;
  constexpr int SCW = CH + 4;      // row stride 68 floats = 272 B (16-B aligned rows)
  int chunk = blockIdx.x, bh = blockIdx.y;
  int b = bh >> 3, h = bh & 7;
  int tid = threadIdx.x;
  __shared__ __align__(16) float qs[Uc * 64];
  __shared__ __align__(16) float sc[48][SCW];
  {
    const float4* qg4 = (const float4*)qg;
    float4* qs4w = (float4*)qs;
    for (int e = tid; e < Uc * 16; e += 256) qs4w[e] = qg4[bh * Uc * 16 + e];
  }
  for (int e = tid; e < 3 * SCW; e += 256) sc[45 + e / SCW][e % SCW] = 0.f;
  __syncthreads();
  {
    int k = tid % CH, tg = tid / CH;
    int key = chunk * CH + k;
    const float4* K4 = (const float4*)K;
    int kb = ((b * Lc + key) * Hc + h) * 16;
    float4 kr[16];
    #pragma unroll
    for (int j = 0; j < 16; ++j) kr[j] = K4[kb + j];
    int mk = amask[b * Lc + key];
    const float4* qs4 = (const float4*)qs;
    for (int t = tg; t < Uc; t += TG) {
      float a0 = 0.f, a1 = 0.f, a2 = 0.f, a3 = 0.f;   // 4 independent fmaf chains
      #pragma unroll
      for (int j = 0; j < 16; j += 4) {
        a0 = dot4_acc(qs4[t * 16 + j],     kr[j],     a0);
        a1 = dot4_acc(qs4[t * 16 + j + 1], kr[j + 1], a1);
        a2 = dot4_acc(qs4[t * 16 + j + 2], kr[j + 2], a2);
        a3 = dot4_acc(qs4[t * 16 + j + 3], kr[j + 3], a3);
      }
      float acc = (a0 + a1) + (a2 + a3);
      sc[t][k] = mk ? acc * 0.125f : -INFINITY;
    }
  }
  __syncthreads();
  {
    // CH=64: one wave per score row; DPP reductions (VALU pipe).
    int w = tid >> 6, lane = tid & 63;
    for (int t = w; t < Uc; t += 4) {
      float x = sc[t][lane];
      float ml = wave_max_bcast(x);
      float p = (ml != -INFINITY) ? __expf(x - ml) : 0.f;   // fully-masked chunk guard
      sc[t][lane] = p;
      float ls = wave_sum_bcast(p);
      if (lane == 0) {
        pM[(bh * NC + chunk) * Uc + t] = ml;
        pL[(bh * NC + chunk) * Uc + t] = ls;
      }
    }
  }
  __syncthreads();
  {
    int ty = tid >> 4, tx = tid & 15;
    float4 o0 = {0.f, 0.f, 0.f, 0.f};
    float4 o1 = {0.f, 0.f, 0.f, 0.f};
    float4 o2 = {0.f, 0.f, 0.f, 0.f};
    const float4* V4 = (const float4*)V;
    const float4* s0 = (const float4*)&sc[ty][0];        // rows 16-B aligned (SCW=68)
    const float4* s1 = (const float4*)&sc[ty + 16][0];
    const float4* s2 = (const float4*)&sc[ty + 32][0];
    int vbase = (b * Lc + chunk * CH) * (Hc * 16) + h * 16 + tx;
    #pragma unroll 2
    for (int kq = 0; kq < CH / 4; ++kq) {
      float4 p0 = s0[kq], p1 = s1[kq], p2 = s2[kq];      // 4 keys per ds_read_b128
      float4 va = V4[vbase + (4 * kq + 0) * (Hc * 16)];
      float4 vb = V4[vbase + (4 * kq + 1) * (Hc * 16)];
      float4 vc = V4[vbase + (4 * kq + 2) * (Hc * 16)];
      float4 vd = V4[vbase + (4 * kq + 3) * (Hc * 16)];
      o0.x = fmaf(p0.x, va.x, o0.x); o0.y = fmaf(p0.x, va.y, o0.y); o0.z = fmaf(p0.x, va.z, o0.z); o0.w = fmaf(p0.x, va.w, o0.w);
      o1.x = fmaf(p1.x, va.x, o1.x); o1.y = fmaf(p1.x, va.y, o1.y); o1.z = fmaf(p1.x, va.z, o1.z); o1.w = fmaf(p1.x, va.w, o1.w);
      o2.x = fmaf(p2.x, va.x, o2.x); o2.y = fmaf(p2.x, va.y, o2.y); o2.z = fmaf(p2.x, va.z, o2.z); o2.w = fmaf(p2.x, va.w, o2.w);
      o0.x = fmaf(p0.y, vb.x, o0.x); o0.y = fmaf(p0.y, vb.y, o0.y); o0.z = fmaf(p0.y, vb.z, o0.z); o0.w = fmaf(p0.y, vb.w, o0.w);
      o1.x = fmaf(p1.y, vb.x, o1.x); o1.y = fmaf(p1.y, vb.y, o1.y); o1.z = fmaf(p1.y, vb.z, o1.z); o1.w = fmaf(p1.y, vb.w, o1.w);
      o2.x = fmaf(p2.y, vb.x, o2.x); o2.y = fmaf(p2.y, vb.y, o2.y); o2.z = fmaf(p2.y, vb.z, o2.z); o2.w = fmaf(p2.y, vb.w, o2.w);
      o0.x = fmaf(p0.z, vc.x, o0.x); o0.y = fmaf(p0.z, vc.y, o0.y); o0.z = fmaf(p0.z, vc.z, o0.z); o0.w = fmaf(p0.z, vc.w, o0.w);
      o1.x = fmaf(p1.z, vc.x, o1.x); o1.y = fmaf(p1.z, vc.y, o1.y); o1.z = fmaf(p1.z, vc.z, o1.z); o1.w = fmaf(p1.z, vc.w, o1.w);
      o2.x = fmaf(p2.z, vc.x, o2.x); o2.y = fmaf(p2.z, vc.y, o2.y); o2.z = fmaf(p2.z, vc.z, o2.z); o2.w = fmaf(p2.z, vc.w, o2.w);
      o0.x = fmaf(p0.w, vd.x, o0.x); o0.y = fmaf(p0.w, vd.y, o0.y); o0.z = fmaf(p0.w, vd.z, o0.z); o0.w = fmaf(p0.w, vd.w, o0.w);
      o1.x = fmaf(p1.w, vd.x, o1.x); o1.y = fmaf(p1.w, vd.y, o1.y); o1.z = fmaf(p1.w, vd.z, o1.z); o1.w = fmaf(p1.w, vd.w, o1.w);
      o2.x = fmaf(p2.w, vd.x, o2.x); o2.y = fmaf(p2.w, vd.y, o2.y); o2.z = fmaf(p2.w, vd.z, o2.z); o2.w = fmaf(p2.w, vd.w, o2.w);
    }
    float4* pO4 = (float4*)pO;
    int obase = ((bh * NC + chunk) * Uc) * 16 + tx;
    pO4[obase + ty * 16] = o0;
    pO4[obase + (ty + 16) * 16] = o1;
    if (ty < 13) pO4[obase + (ty + 32) * 16] = o2;
  }
}

// Exact merge of chunk partials; out[b][t][h][d].
template<int NC>
__global__ __launch_bounds__(256) void k_merge(const float* __restrict__ pO, const float* __restrict__ pM,
                                               const float* __restrict__ pL, float* __restrict__ out) {
  int f = blockIdx.x * 256 + threadIdx.x;   // 180*256 == 46080
  int d = f & 63, h = (f >> 6) & 7;
  int bt = f >> 9;
  int t = bt % Uc, b = bt / Uc;
  int bh = b * 8 + h;
  float m = -INFINITY;
  for (int c = 0; c < NC; ++c) m = fmaxf(m, pM[(bh * NC + c) * Uc + t]);
  float den = 0.f, num = 0.f;
  for (int c = 0; c < NC; ++c) {
    float mc = pM[(bh * NC + c) * Uc + t];
    float wgt = (mc == -INFINITY) ? 0.f : __expf(mc - m);
    den += wgt * pL[(bh * NC + c) * Uc + t];
    num += wgt * pO[((bh * NC + c) * Uc + t) * 64 + d];
  }
  out[f] = num / den;
}

extern "C" void kernel_launch(void* const* d_in, const int* in_sizes, int n_in,
                              void* d_out, int out_size, void* d_ws, size_t ws_size,
                              hipStream_t stream) {
  const float* Q = (const float*)d_in[0];
  const float* K = (const float*)d_in[1];
  const float* V = (const float*)d_in[2];
  const int* amask = (const int*)d_in[3];
  float* out = (float*)d_out;
  char* ws = (char*)d_ws;
  float* M    = (float*)(ws + 0x000000);   // 65536 floats (256 KB)
  int*   topk = (int*)(ws + 0x040000);     // 720 ints
  float* qg   = (float*)(ws + 0x041000);   // 16*45*64 floats (184,320 B)
  int*   gidx = (int*)(ws + 0x070000);     // 184320 ints (737,280 B) idx table
  float* pM   = (float*)(ws + 0x130000);
  // ws_size is constant across calls -> branch is deterministic (graph-safe).
  size_t need64 = 0x130000UL + 64UL * 190080UL;   // pM+pL+pO for NC=64 (~13.4 MB)
  size_t need32 = 0x130000UL + 32UL * 190080UL;
  int NC = ws_size >= need64 ? 64 : (ws_size >= need32 ? 32 : 16);
  float* pL = pM + 16 * NC * Uc;
  float* pO = pL + 16 * NC * Uc;

  k_genidx<<<720, 256, 0, stream>>>(gidx);
  k_scoreM<<<1024, 256, 0, stream>>>(Q, K, gidx, M);
  k_topk<<<BHc, 256, 0, stream>>>(M, Q, topk, qg);
  if (NC == 64) {
    k_attn<64><<<dim3(64, BHc), 256, 0, stream>>>(qg, K, V, amask, pO, pM, pL);
    k_merge<64><<<180, 256, 0, stream>>>(pO, pM, pL, out);
  } else if (NC == 32) {
    k_attn<32><<<dim3(32, BHc), 256, 0, stream>>>(qg, K, V, amask, pO, pM, pL);
    k_merge<32><<<180, 256, 0, stream>>>(pO, pM, pL, out);
  } else {
    k_attn<16><<<dim3(16, BHc), 256, 0, stream>>>(qg, K, V, amask, pO, pM, pL);
    k_merge<16><<<180, 256, 0, stream>>>(pO, pM, pL, out);
  }
}

// Round 2
// 193.928 us; speedup vs baseline: 1.2372x; 1.2372x over previous
//
#include <hip/hip_runtime.h>
#include <math.h>

// ProbSparse attention (Informer). B=2 L=4096 H=8 D=64, U_part=u=45.
// R10: R8 geometry restored (4096 blocks, 16 q/block, 16 lanes/query, 5-deep
// batches, nontemporal K loads) + R9's k_genidx hoist kept. R9 post-mortem:
// the 4-lane layout kept line count but cut wave concurrency 4x (16K->4K
// waves) and stretched the per-block reuse window -> latency-bound (VALUBusy
// 7.8%) + L2 thrash (FETCH 18->85 MB). This round changes ONLY the idx
// source vs R8: ~310 wave-insts of threefry per wave -> 3 vector loads.
// Discriminator: scoreM ~38us => L2-line-rate floor confirmed (next: CSR
// dedup, 0.36x lines); ~28us => VALU-bound theory wins.
#define JAX_PARTITIONABLE 1

constexpr int Bc = 2, Lc = 4096, Hc = 8, Dc = 64;
constexpr int BHc = Bc * Hc;     // 16
constexpr int Uc = 45;           // top-k queries
constexpr int NSc = 45;          // samples per query

typedef float vfloat4 __attribute__((ext_vector_type(4)));

struct TF2 { unsigned a, b; };

__host__ __device__ constexpr unsigned rotl32(unsigned v, int n) {
  return (v << n) | (v >> (32 - n));
}

// Threefry-2x32, 20 rounds (JAX reference schedule).
__host__ __device__ constexpr TF2 tf2(unsigned k0, unsigned k1, unsigned x0, unsigned x1) {
  unsigned ks2 = k0 ^ k1 ^ 0x1BD11BDAu;
  x0 += k0; x1 += k1;
  x0 += x1; x1 = rotl32(x1, 13); x1 ^= x0;
  x0 += x1; x1 = rotl32(x1, 15); x1 ^= x0;
  x0 += x1; x1 = rotl32(x1, 26); x1 ^= x0;
  x0 += x1; x1 = rotl32(x1, 6);  x1 ^= x0;
  x0 += k1; x1 += ks2 + 1u;
  x0 += x1; x1 = rotl32(x1, 17); x1 ^= x0;
  x0 += x1; x1 = rotl32(x1, 29); x1 ^= x0;
  x0 += x1; x1 = rotl32(x1, 16); x1 ^= x0;
  x0 += x1; x1 = rotl32(x1, 24); x1 ^= x0;
  x0 += ks2; x1 += k0 + 2u;
  x0 += x1; x1 = rotl32(x1, 13); x1 ^= x0;
  x0 += x1; x1 = rotl32(x1, 15); x1 ^= x0;
  x0 += x1; x1 = rotl32(x1, 26); x1 ^= x0;
  x0 += x1; x1 = rotl32(x1, 6);  x1 ^= x0;
  x0 += k0; x1 += k1 + 3u;
  x0 += x1; x1 = rotl32(x1, 17); x1 ^= x0;
  x0 += x1; x1 = rotl32(x1, 29); x1 ^= x0;
  x0 += x1; x1 = rotl32(x1, 16); x1 ^= x0;
  x0 += x1; x1 = rotl32(x1, 24); x1 ^= x0;
  x0 += k1; x1 += ks2 + 4u;
  x0 += x1; x1 = rotl32(x1, 13); x1 ^= x0;
  x0 += x1; x1 = rotl32(x1, 15); x1 ^= x0;
  x0 += x1; x1 = rotl32(x1, 26); x1 ^= x0;
  x0 += x1; x1 = rotl32(x1, 6);  x1 ^= x0;
  x0 += ks2; x1 += k0 + 5u;
  return TF2{x0, x1};
}

// VALU-pipe partial-sum add via DPP (identity old=0 for invalid lanes).
template <int CTRL>
__device__ __forceinline__ float dpp_add(float x) {
  int t = __builtin_amdgcn_update_dpp(0, __float_as_int(x), CTRL, 0xF, 0xF, false);
  return x + __int_as_float(t);
}
// DPP-shifted value with own value as identity for invalid lanes (for max).
template <int CTRL>
__device__ __forceinline__ float dpp_idf(float x) {
  int t = __builtin_amdgcn_update_dpp(__float_as_int(x), __float_as_int(x), CTRL, 0xF, 0xF, false);
  return __int_as_float(t);
}
// Full-wave (64-lane) max/sum: result valid at lane 63, broadcast via readlane.
__device__ __forceinline__ float wave_max_bcast(float x) {
  x = fmaxf(x, dpp_idf<0x111>(x));   // row_shr:1
  x = fmaxf(x, dpp_idf<0x112>(x));   // row_shr:2
  x = fmaxf(x, dpp_idf<0x114>(x));   // row_shr:4
  x = fmaxf(x, dpp_idf<0x118>(x));   // row_shr:8  -> lane15 of each row = row max
  x = fmaxf(x, dpp_idf<0x142>(x));   // row_bcast:15
  x = fmaxf(x, dpp_idf<0x143>(x));   // row_bcast:31 -> lane63 = wave max
  return __int_as_float(__builtin_amdgcn_readlane(__float_as_int(x), 63));
}
__device__ __forceinline__ float wave_sum_bcast(float x) {
  x = dpp_add<0x111>(x);
  x = dpp_add<0x112>(x);
  x = dpp_add<0x114>(x);
  x = dpp_add<0x118>(x);
  x = dpp_add<0x142>(x);
  x = dpp_add<0x143>(x);
  return __int_as_float(__builtin_amdgcn_readlane(__float_as_int(x), 63));
}

// fmaf chain for a float4 dot accumulated into a: 4 VALU insts.
__device__ __forceinline__ float dot4_acc(float4 q, float4 k, float a) {
  a = fmaf(q.x, k.x, a);
  a = fmaf(q.y, k.y, a);
  a = fmaf(q.z, k.z, a);
  a = fmaf(q.w, k.w, a);
  return a;
}

// Precompute the sample-index table once (bh-independent; was hashed 16x
// redundantly inside k_scoreM). g = q*45 + s, exact same counter mapping.
__global__ __launch_bounds__(256) void k_genidx(int* __restrict__ gidx) {
  unsigned g = blockIdx.x * 256u + threadIdx.x;   // 720*256 == 184320 exactly
  constexpr TF2 kb = tf2(0u, 1u, 0u, 1u);
  TF2 r = tf2(kb.a, kb.b, 0u, g);
  gidx[g] = (int)((r.a ^ r.b) & 4095u);
}

// M[bh][q] = max_s dot(Q[q],K[idx[q][s]]) - sum_s(...)/4096.
// bh = blockIdx&15: with round-robin block->XCD dispatch, each XCD sees 2 bh
// -> 2 MB K slices stay L2-resident. R8 geometry exactly; idx from gidx.
__global__ __launch_bounds__(256) void k_scoreM(const float* __restrict__ Q, const float* __restrict__ K,
                                                const int* __restrict__ gidx, float* __restrict__ M) {
  __shared__ int sidx[720];
  int tid = threadIdx.x;
  int bx = blockIdx.x;
  int bh = bx & 15;
  int qblk = bx >> 4;              // 0..255
  int b = bh >> 3, h = bh & 7;
  int lane16 = tid & 15, qloc = tid >> 4;
  int q = qblk * 16 + qloc;
  {
    // 720 ints = 180 int4; qblk*720 ints = qblk*2880 B (16-B aligned).
    const int4* g4 = (const int4*)(gidx + qblk * 720);
    int4* s4 = (int4*)sidx;
    for (int e = tid; e < 180; e += 256) s4[e] = g4[e];
  }
  __syncthreads();
  const vfloat4* Q4 = (const vfloat4*)Q;
  const vfloat4* K4 = (const vfloat4*)K;
  vfloat4 qr = Q4[((b * Lc + q) * Hc + h) * 16 + lane16];
  int kbase = (b * Lc * Hc + h) * 16 + lane16;
  const int* ip = sidx + qloc * NSc;
  float mx = -INFINITY, sm = 0.f;
  #pragma unroll
  for (int s0 = 0; s0 < NSc; s0 += 5) {      // 5-deep load batch: L2 loads in flight
    int kk[5];
    #pragma unroll
    for (int i = 0; i < 5; ++i) kk[i] = ip[s0 + i];
    vfloat4 kv[5];
    #pragma unroll
    for (int i = 0; i < 5; ++i) kv[i] = __builtin_nontemporal_load(&K4[kbase + kk[i] * (Hc * 16)]);
    #pragma unroll
    for (int i = 0; i < 5; ++i) {
      float p = fmaf(qr[0], kv[i][0], fmaf(qr[1], kv[i][1], fmaf(qr[2], kv[i][2], qr[3] * kv[i][3])));
      p = dpp_add<0x111>(p);                 // row_shr cascade -> lane15 = full dot
      p = dpp_add<0x112>(p);
      p = dpp_add<0x114>(p);
      p = dpp_add<0x118>(p);
      mx = fmaxf(mx, p);                     // valid at lane15; junk elsewhere (never read)
      sm += p;
    }
  }
  if (lane16 == 15) M[bh * Lc + q] = mx - sm * (1.0f / Lc);
}

// Radix-select top-45 of 4096 per bh (exact lax.top_k: value desc, index asc
// on ties). Then pre-gather the 45 selected Q rows into qg[bh][45][64].
__global__ __launch_bounds__(256) void k_topk(const float* __restrict__ M, const float* __restrict__ Q,
                                              int* __restrict__ topk, float* __restrict__ qg) {
  __shared__ unsigned su[Lc];      // 16 KB mapped keys
  __shared__ int hist[256];
  __shared__ int sfx[257];
  __shared__ unsigned s_prefix;
  __shared__ int s_r;
  __shared__ int n_gt, n_eq;
  __shared__ unsigned cu[64];
  __shared__ int cidx[64];
  __shared__ int eqi[64];
  __shared__ int srank[Uc];
  int bh = blockIdx.x, tid = threadIdx.x;
  int b = bh >> 3, h = bh & 7;
  const float* m = M + bh * Lc;
  for (int e = tid; e < Lc; e += 256) {
    unsigned bb = __float_as_uint(m[e]);
    su[e] = (bb & 0x80000000u) ? ~bb : (bb | 0x80000000u);
  }
  if (tid == 0) { s_r = Uc; s_prefix = 0u; n_gt = 0; n_eq = 0; }
  __syncthreads();
  #pragma unroll
  for (int p = 0; p < 4; ++p) {
    int shift = 24 - 8 * p;
    hist[tid] = 0;
    __syncthreads();
    unsigned pref = s_prefix;
    unsigned hmask = (p == 0) ? 0u : (0xFFFFFFFFu << (shift + 8));
    for (int e = tid; e < Lc; e += 256) {
      unsigned u = su[e];
      if ((u & hmask) == pref) atomicAdd(&hist[(u >> shift) & 255u], 1);
    }
    __syncthreads();
    sfx[tid] = hist[tid];
    __syncthreads();
    for (int off = 1; off < 256; off <<= 1) {   // inclusive suffix sum
      int v = (tid + off < 256) ? sfx[tid + off] : 0;
      __syncthreads();
      sfx[tid] += v;
      __syncthreads();
    }
    int r = s_r;
    __syncthreads();                            // all read s_r before update
    int above = (tid < 255) ? sfx[tid + 1] : 0;
    if (sfx[tid] >= r && above < r) {           // unique digit
      s_r = r - above;
      s_prefix = pref | ((unsigned)tid << shift);
    }
    __syncthreads();
  }
  unsigned T = s_prefix;                        // exact 45th-largest key
  int rf = s_r;                                 // #equals to take (>=1)
  for (int e = tid; e < Lc; e += 256) {
    unsigned u = su[e];
    if (u > T) {
      int p = atomicAdd(&n_gt, 1);              // <= 44
      cu[p] = u; cidx[p] = e;
    } else if (u == T) {
      int p = atomicAdd(&n_eq, 1);
      if (p < 64) eqi[p] = e;                   // >64-way ties: impossible for random-normal M
    }
  }
  __syncthreads();
  int ne = n_eq < 64 ? n_eq : 64;
  if (tid < ne) {
    int myi = eqi[tid];
    int rank = 0;
    for (int j = 0; j < ne; ++j) rank += (eqi[j] < myi);
    if (rank < rf) {
      int p = atomicAdd(&n_gt, 1);              // completes to exactly 45
      cu[p] = T; cidx[p] = myi;
    }
  }
  __syncthreads();
  if (tid < Uc) {
    unsigned mu = cu[tid]; int mi = cidx[tid];
    int rank = 0;
    for (int j = 0; j < Uc; ++j) {
      unsigned ju = cu[j]; int ji = cidx[j];
      rank += (ju > mu) || (ju == mu && ji < mi);
    }
    topk[bh * Uc + rank] = mi;
    srank[rank] = mi;
  }
  __syncthreads();
  const float4* Q4 = (const float4*)Q;
  float4* qg4 = (float4*)qg;
  for (int e = tid; e < Uc * 16; e += 256) {    // coalesced pre-gather of selected Q rows
    int t = e >> 4, dq = e & 15;
    qg4[bh * Uc * 16 + e] = Q4[((b * Lc + srank[t]) * Hc + h) * 16 + dq];
  }
}

// Flash-decoding partials: one block per (bh, CH-key chunk), CH = 4096/NC.
// NOTE: phase 2 assumes CH == 64 (one wave per score row); the NC=64 path is
// always taken in practice (ws_size >> 14 MB).
template<int NC>
__global__ __launch_bounds__(256) void k_attn(const float* __restrict__ qg, const float* __restrict__ K,
                                              const float* __restrict__ V, const int* __restrict__ amask,
                                              float* __restrict__ pO, float* __restrict__ pM,
                                              float* __restrict__ pL) {
  constexpr int CH = Lc / NC;
  constexpr int TG = 256 / CH;
  constexpr int SCW = CH + 4;      // row stride 68 floats = 272 B (16-B aligned rows)
  int chunk = blockIdx.x, bh = blockIdx.y;
  int b = bh >> 3, h = bh & 7;
  int tid = threadIdx.x;
  __shared__ __align__(16) float qs[Uc * 64];
  __shared__ __align__(16) float sc[48][SCW];
  {
    const float4* qg4 = (const float4*)qg;
    float4* qs4w = (float4*)qs;
    for (int e = tid; e < Uc * 16; e += 256) qs4w[e] = qg4[bh * Uc * 16 + e];
  }
  for (int e = tid; e < 3 * SCW; e += 256) sc[45 + e / SCW][e % SCW] = 0.f;
  __syncthreads();
  {
    int k = tid % CH, tg = tid / CH;
    int key = chunk * CH + k;
    const float4* K4 = (const float4*)K;
    int kb = ((b * Lc + key) * Hc + h) * 16;
    float4 kr[16];
    #pragma unroll
    for (int j = 0; j < 16; ++j) kr[j] = K4[kb + j];
    int mk = amask[b * Lc + key];
    const float4* qs4 = (const float4*)qs;
    for (int t = tg; t < Uc; t += TG) {
      float a0 = 0.f, a1 = 0.f, a2 = 0.f, a3 = 0.f;   // 4 independent fmaf chains
      #pragma unroll
      for (int j = 0; j < 16; j += 4) {
        a0 = dot4_acc(qs4[t * 16 + j],     kr[j],     a0);
        a1 = dot4_acc(qs4[t * 16 + j + 1], kr[j + 1], a1);
        a2 = dot4_acc(qs4[t * 16 + j + 2], kr[j + 2], a2);
        a3 = dot4_acc(qs4[t * 16 + j + 3], kr[j + 3], a3);
      }
      float acc = (a0 + a1) + (a2 + a3);
      sc[t][k] = mk ? acc * 0.125f : -INFINITY;
    }
  }
  __syncthreads();
  {
    // CH=64: one wave per score row; DPP reductions (VALU pipe).
    int w = tid >> 6, lane = tid & 63;
    for (int t = w; t < Uc; t += 4) {
      float x = sc[t][lane];
      float ml = wave_max_bcast(x);
      float p = (ml != -INFINITY) ? __expf(x - ml) : 0.f;   // fully-masked chunk guard
      sc[t][lane] = p;
      float ls = wave_sum_bcast(p);
      if (lane == 0) {
        pM[(bh * NC + chunk) * Uc + t] = ml;
        pL[(bh * NC + chunk) * Uc + t] = ls;
      }
    }
  }
  __syncthreads();
  {
    int ty = tid >> 4, tx = tid & 15;
    float4 o0 = {0.f, 0.f, 0.f, 0.f};
    float4 o1 = {0.f, 0.f, 0.f, 0.f};
    float4 o2 = {0.f, 0.f, 0.f, 0.f};
    const float4* V4 = (const float4*)V;
    const float4* s0 = (const float4*)&sc[ty][0];        // rows 16-B aligned (SCW=68)
    const float4* s1 = (const float4*)&sc[ty + 16][0];
    const float4* s2 = (const float4*)&sc[ty + 32][0];
    int vbase = (b * Lc + chunk * CH) * (Hc * 16) + h * 16 + tx;
    #pragma unroll 2
    for (int kq = 0; kq < CH / 4; ++kq) {
      float4 p0 = s0[kq], p1 = s1[kq], p2 = s2[kq];      // 4 keys per ds_read_b128
      float4 va = V4[vbase + (4 * kq + 0) * (Hc * 16)];
      float4 vb = V4[vbase + (4 * kq + 1) * (Hc * 16)];
      float4 vc = V4[vbase + (4 * kq + 2) * (Hc * 16)];
      float4 vd = V4[vbase + (4 * kq + 3) * (Hc * 16)];
      o0.x = fmaf(p0.x, va.x, o0.x); o0.y = fmaf(p0.x, va.y, o0.y); o0.z = fmaf(p0.x, va.z, o0.z); o0.w = fmaf(p0.x, va.w, o0.w);
      o1.x = fmaf(p1.x, va.x, o1.x); o1.y = fmaf(p1.x, va.y, o1.y); o1.z = fmaf(p1.x, va.z, o1.z); o1.w = fmaf(p1.x, va.w, o1.w);
      o2.x = fmaf(p2.x, va.x, o2.x); o2.y = fmaf(p2.x, va.y, o2.y); o2.z = fmaf(p2.x, va.z, o2.z); o2.w = fmaf(p2.x, va.w, o2.w);
      o0.x = fmaf(p0.y, vb.x, o0.x); o0.y = fmaf(p0.y, vb.y, o0.y); o0.z = fmaf(p0.y, vb.z, o0.z); o0.w = fmaf(p0.y, vb.w, o0.w);
      o1.x = fmaf(p1.y, vb.x, o1.x); o1.y = fmaf(p1.y, vb.y, o1.y); o1.z = fmaf(p1.y, vb.z, o1.z); o1.w = fmaf(p1.y, vb.w, o1.w);
      o2.x = fmaf(p2.y, vb.x, o2.x); o2.y = fmaf(p2.y, vb.y, o2.y); o2.z = fmaf(p2.y, vb.z, o2.z); o2.w = fmaf(p2.y, vb.w, o2.w);
      o0.x = fmaf(p0.z, vc.x, o0.x); o0.y = fmaf(p0.z, vc.y, o0.y); o0.z = fmaf(p0.z, vc.z, o0.z); o0.w = fmaf(p0.z, vc.w, o0.w);
      o1.x = fmaf(p1.z, vc.x, o1.x); o1.y = fmaf(p1.z, vc.y, o1.y); o1.z = fmaf(p1.z, vc.z, o1.z); o1.w = fmaf(p1.z, vc.w, o1.w);
      o2.x = fmaf(p2.z, vc.x, o2.x); o2.y = fmaf(p2.z, vc.y, o2.y); o2.z = fmaf(p2.z, vc.z, o2.z); o2.w = fmaf(p2.z, vc.w, o2.w);
      o0.x = fmaf(p0.w, vd.x, o0.x); o0.y = fmaf(p0.w, vd.y, o0.y); o0.z = fmaf(p0.w, vd.z, o0.z); o0.w = fmaf(p0.w, vd.w, o0.w);
      o1.x = fmaf(p1.w, vd.x, o1.x); o1.y = fmaf(p1.w, vd.y, o1.y); o1.z = fmaf(p1.w, vd.z, o1.z); o1.w = fmaf(p1.w, vd.w, o1.w);
      o2.x = fmaf(p2.w, vd.x, o2.x); o2.y = fmaf(p2.w, vd.y, o2.y); o2.z = fmaf(p2.w, vd.z, o2.z); o2.w = fmaf(p2.w, vd.w, o2.w);
    }
    float4* pO4 = (float4*)pO;
    int obase = ((bh * NC + chunk) * Uc) * 16 + tx;
    pO4[obase + ty * 16] = o0;
    pO4[obase + (ty + 16) * 16] = o1;
    if (ty < 13) pO4[obase + (ty + 32) * 16] = o2;
  }
}

// Exact merge of chunk partials; out[b][t][h][d].
template<int NC>
__global__ __launch_bounds__(256) void k_merge(const float* __restrict__ pO, const float* __restrict__ pM,
                                               const float* __restrict__ pL, float* __restrict__ out) {
  int f = blockIdx.x * 256 + threadIdx.x;   // 180*256 == 46080
  int d = f & 63, h = (f >> 6) & 7;
  int bt = f >> 9;
  int t = bt % Uc, b = bt / Uc;
  int bh = b * 8 + h;
  float m = -INFINITY;
  for (int c = 0; c < NC; ++c) m = fmaxf(m, pM[(bh * NC + c) * Uc + t]);
  float den = 0.f, num = 0.f;
  for (int c = 0; c < NC; ++c) {
    float mc = pM[(bh * NC + c) * Uc + t];
    float wgt = (mc == -INFINITY) ? 0.f : __expf(mc - m);
    den += wgt * pL[(bh * NC + c) * Uc + t];
    num += wgt * pO[((bh * NC + c) * Uc + t) * 64 + d];
  }
  out[f] = num / den;
}

extern "C" void kernel_launch(void* const* d_in, const int* in_sizes, int n_in,
                              void* d_out, int out_size, void* d_ws, size_t ws_size,
                              hipStream_t stream) {
  const float* Q = (const float*)d_in[0];
  const float* K = (const float*)d_in[1];
  const float* V = (const float*)d_in[2];
  const int* amask = (const int*)d_in[3];
  float* out = (float*)d_out;
  char* ws = (char*)d_ws;
  float* M    = (float*)(ws + 0x000000);   // 65536 floats (256 KB)
  int*   topk = (int*)(ws + 0x040000);     // 720 ints
  float* qg   = (float*)(ws + 0x041000);   // 16*45*64 floats (184,320 B)
  int*   gidx = (int*)(ws + 0x070000);     // 184320 ints (737,280 B) idx table
  float* pM   = (float*)(ws + 0x130000);
  // ws_size is constant across calls -> branch is deterministic (graph-safe).
  size_t need64 = 0x130000UL + 64UL * 190080UL;   // pM+pL+pO for NC=64 (~13.4 MB)
  size_t need32 = 0x130000UL + 32UL * 190080UL;
  int NC = ws_size >= need64 ? 64 : (ws_size >= need32 ? 32 : 16);
  float* pL = pM + 16 * NC * Uc;
  float* pO = pL + 16 * NC * Uc;

  k_genidx<<<720, 256, 0, stream>>>(gidx);
  k_scoreM<<<4096, 256, 0, stream>>>(Q, K, gidx, M);
  k_topk<<<BHc, 256, 0, stream>>>(M, Q, topk, qg);
  if (NC == 64) {
    k_attn<64><<<dim3(64, BHc), 256, 0, stream>>>(qg, K, V, amask, pO, pM, pL);
    k_merge<64><<<180, 256, 0, stream>>>(pO, pM, pL, out);
  } else if (NC == 32) {
    k_attn<32><<<dim3(32, BHc), 256, 0, stream>>>(qg, K, V, amask, pO, pM, pL);
    k_merge<32><<<180, 256, 0, stream>>>(pO, pM, pL, out);
  } else {
    k_attn<16><<<dim3(16, BHc), 256, 0, stream>>>(qg, K, V, amask, pO, pM, pL);
    k_merge<16><<<180, 256, 0, stream>>>(pO, pM, pL, out);
  }
}

// Round 4
// 191.563 us; speedup vs baseline: 1.2525x; 1.0123x over previous
//
#include <hip/hip_runtime.h>
#include <math.h>

// ProbSparse attention (Informer). B=2 L=4096 H=8 D=64, U_part=u=45.
// R11b: compile fix only (vint4 ext-vector for nontemporal gidx load).
// R11 theory: R10's genidx hoist kept the VALU cut (57->33%) but gidx
// streaming polluted L2 (per-XCD set 2MB K + 2MB Q == 4MB L2 exactly);
// nt-hinted K became the eviction victim -> FETCH 18->54MB, scoreM 43->53us.
// Fix: (a) gidx compressed to u16 (360KB table); (b) gidx loads nontemporal
// (evict-first) so K keeps L2 residency. scoreM geometry byte-identical to
// R8. Prediction: FETCH ~18-20MB, scoreM 38-41us (L2 line-rate floor),
// total ~175us. If FETCH stays high -> pollution theory wrong, revert to
// R8 in-kernel threefry next round.
#define JAX_PARTITIONABLE 1

constexpr int Bc = 2, Lc = 4096, Hc = 8, Dc = 64;
constexpr int BHc = Bc * Hc;     // 16
constexpr int Uc = 45;           // top-k queries
constexpr int NSc = 45;          // samples per query

typedef float vfloat4 __attribute__((ext_vector_type(4)));
typedef int vint4 __attribute__((ext_vector_type(4)));

struct TF2 { unsigned a, b; };

__host__ __device__ constexpr unsigned rotl32(unsigned v, int n) {
  return (v << n) | (v >> (32 - n));
}

// Threefry-2x32, 20 rounds (JAX reference schedule).
__host__ __device__ constexpr TF2 tf2(unsigned k0, unsigned k1, unsigned x0, unsigned x1) {
  unsigned ks2 = k0 ^ k1 ^ 0x1BD11BDAu;
  x0 += k0; x1 += k1;
  x0 += x1; x1 = rotl32(x1, 13); x1 ^= x0;
  x0 += x1; x1 = rotl32(x1, 15); x1 ^= x0;
  x0 += x1; x1 = rotl32(x1, 26); x1 ^= x0;
  x0 += x1; x1 = rotl32(x1, 6);  x1 ^= x0;
  x0 += k1; x1 += ks2 + 1u;
  x0 += x1; x1 = rotl32(x1, 17); x1 ^= x0;
  x0 += x1; x1 = rotl32(x1, 29); x1 ^= x0;
  x0 += x1; x1 = rotl32(x1, 16); x1 ^= x0;
  x0 += x1; x1 = rotl32(x1, 24); x1 ^= x0;
  x0 += ks2; x1 += k0 + 2u;
  x0 += x1; x1 = rotl32(x1, 13); x1 ^= x0;
  x0 += x1; x1 = rotl32(x1, 15); x1 ^= x0;
  x0 += x1; x1 = rotl32(x1, 26); x1 ^= x0;
  x0 += x1; x1 = rotl32(x1, 6);  x1 ^= x0;
  x0 += k0; x1 += k1 + 3u;
  x0 += x1; x1 = rotl32(x1, 17); x1 ^= x0;
  x0 += x1; x1 = rotl32(x1, 29); x1 ^= x0;
  x0 += x1; x1 = rotl32(x1, 16); x1 ^= x0;
  x0 += x1; x1 = rotl32(x1, 24); x1 ^= x0;
  x0 += k1; x1 += ks2 + 4u;
  x0 += x1; x1 = rotl32(x1, 13); x1 ^= x0;
  x0 += x1; x1 = rotl32(x1, 15); x1 ^= x0;
  x0 += x1; x1 = rotl32(x1, 26); x1 ^= x0;
  x0 += x1; x1 = rotl32(x1, 6);  x1 ^= x0;
  x0 += ks2; x1 += k0 + 5u;
  return TF2{x0, x1};
}

// VALU-pipe partial-sum add via DPP (identity old=0 for invalid lanes).
template <int CTRL>
__device__ __forceinline__ float dpp_add(float x) {
  int t = __builtin_amdgcn_update_dpp(0, __float_as_int(x), CTRL, 0xF, 0xF, false);
  return x + __int_as_float(t);
}
// DPP-shifted value with own value as identity for invalid lanes (for max).
template <int CTRL>
__device__ __forceinline__ float dpp_idf(float x) {
  int t = __builtin_amdgcn_update_dpp(__float_as_int(x), __float_as_int(x), CTRL, 0xF, 0xF, false);
  return __int_as_float(t);
}
// Full-wave (64-lane) max/sum: result valid at lane 63, broadcast via readlane.
__device__ __forceinline__ float wave_max_bcast(float x) {
  x = fmaxf(x, dpp_idf<0x111>(x));   // row_shr:1
  x = fmaxf(x, dpp_idf<0x112>(x));   // row_shr:2
  x = fmaxf(x, dpp_idf<0x114>(x));   // row_shr:4
  x = fmaxf(x, dpp_idf<0x118>(x));   // row_shr:8  -> lane15 of each row = row max
  x = fmaxf(x, dpp_idf<0x142>(x));   // row_bcast:15
  x = fmaxf(x, dpp_idf<0x143>(x));   // row_bcast:31 -> lane63 = wave max
  return __int_as_float(__builtin_amdgcn_readlane(__float_as_int(x), 63));
}
__device__ __forceinline__ float wave_sum_bcast(float x) {
  x = dpp_add<0x111>(x);
  x = dpp_add<0x112>(x);
  x = dpp_add<0x114>(x);
  x = dpp_add<0x118>(x);
  x = dpp_add<0x142>(x);
  x = dpp_add<0x143>(x);
  return __int_as_float(__builtin_amdgcn_readlane(__float_as_int(x), 63));
}

// fmaf chain for a float4 dot accumulated into a: 4 VALU insts.
__device__ __forceinline__ float dot4_acc(float4 q, float4 k, float a) {
  a = fmaf(q.x, k.x, a);
  a = fmaf(q.y, k.y, a);
  a = fmaf(q.z, k.z, a);
  a = fmaf(q.w, k.w, a);
  return a;
}

// Precompute the sample-index table once (bh-independent; was hashed 16x
// redundantly inside k_scoreM). Packed u16 pairs: table 360KB (was 737KB).
// Element g = q*45 + s keeps the exact verified counter mapping.
__global__ __launch_bounds__(256) void k_genidx(unsigned* __restrict__ gidx) {
  unsigned t = blockIdx.x * 256u + threadIdx.x;   // 360*256 == 92160
  unsigned g = t * 2u;
  constexpr TF2 kb = tf2(0u, 1u, 0u, 1u);
  TF2 r0 = tf2(kb.a, kb.b, 0u, g);
  TF2 r1 = tf2(kb.a, kb.b, 0u, g + 1u);
  unsigned h0 = (r0.a ^ r0.b) & 4095u;
  unsigned h1 = (r1.a ^ r1.b) & 4095u;
  gidx[t] = h0 | (h1 << 16);
}

// M[bh][q] = max_s dot(Q[q],K[idx[q][s]]) - sum_s(...)/4096.
// bh = blockIdx&15: with round-robin block->XCD dispatch, each XCD sees 2 bh
// -> 2 MB K slices stay L2-resident. R8 geometry exactly; idx from u16 gidx
// via nontemporal loads (evict-first: don't displace K/Q in L2).
__global__ __launch_bounds__(256) void k_scoreM(const float* __restrict__ Q, const float* __restrict__ K,
                                                const unsigned* __restrict__ gidx, float* __restrict__ M) {
  __shared__ int sidx[720];
  int tid = threadIdx.x;
  int bx = blockIdx.x;
  int bh = bx & 15;
  int qblk = bx >> 4;              // 0..255
  int b = bh >> 3, h = bh & 7;
  int lane16 = tid & 15, qloc = tid >> 4;
  int q = qblk * 16 + qloc;
  {
    // 720 u16 = 1440 B per qblk (16-B aligned: 1440 = 90*16). 90 vint4 loads.
    const vint4* g4 = (const vint4*)((const char*)gidx + qblk * 1440);
    for (int e = tid; e < 90; e += 256) {
      vint4 v = __builtin_nontemporal_load(&g4[e]);
      int base = e * 8;
      unsigned w0 = (unsigned)v[0], w1 = (unsigned)v[1], w2 = (unsigned)v[2], w3 = (unsigned)v[3];
      sidx[base + 0] = (int)(w0 & 0xFFFFu); sidx[base + 1] = (int)(w0 >> 16);
      sidx[base + 2] = (int)(w1 & 0xFFFFu); sidx[base + 3] = (int)(w1 >> 16);
      sidx[base + 4] = (int)(w2 & 0xFFFFu); sidx[base + 5] = (int)(w2 >> 16);
      sidx[base + 6] = (int)(w3 & 0xFFFFu); sidx[base + 7] = (int)(w3 >> 16);
    }
  }
  __syncthreads();
  const vfloat4* Q4 = (const vfloat4*)Q;
  const vfloat4* K4 = (const vfloat4*)K;
  vfloat4 qr = Q4[((b * Lc + q) * Hc + h) * 16 + lane16];
  int kbase = (b * Lc * Hc + h) * 16 + lane16;
  const int* ip = sidx + qloc * NSc;
  float mx = -INFINITY, sm = 0.f;
  #pragma unroll
  for (int s0 = 0; s0 < NSc; s0 += 5) {      // 5-deep load batch: L2 loads in flight
    int kk[5];
    #pragma unroll
    for (int i = 0; i < 5; ++i) kk[i] = ip[s0 + i];
    vfloat4 kv[5];
    #pragma unroll
    for (int i = 0; i < 5; ++i) kv[i] = __builtin_nontemporal_load(&K4[kbase + kk[i] * (Hc * 16)]);
    #pragma unroll
    for (int i = 0; i < 5; ++i) {
      float p = fmaf(qr[0], kv[i][0], fmaf(qr[1], kv[i][1], fmaf(qr[2], kv[i][2], qr[3] * kv[i][3])));
      p = dpp_add<0x111>(p);                 // row_shr cascade -> lane15 = full dot
      p = dpp_add<0x112>(p);
      p = dpp_add<0x114>(p);
      p = dpp_add<0x118>(p);
      mx = fmaxf(mx, p);                     // valid at lane15; junk elsewhere (never read)
      sm += p;
    }
  }
  if (lane16 == 15) M[bh * Lc + q] = mx - sm * (1.0f / Lc);
}

// Radix-select top-45 of 4096 per bh (exact lax.top_k: value desc, index asc
// on ties). Then pre-gather the 45 selected Q rows into qg[bh][45][64].
__global__ __launch_bounds__(256) void k_topk(const float* __restrict__ M, const float* __restrict__ Q,
                                              int* __restrict__ topk, float* __restrict__ qg) {
  __shared__ unsigned su[Lc];      // 16 KB mapped keys
  __shared__ int hist[256];
  __shared__ int sfx[257];
  __shared__ unsigned s_prefix;
  __shared__ int s_r;
  __shared__ int n_gt, n_eq;
  __shared__ unsigned cu[64];
  __shared__ int cidx[64];
  __shared__ int eqi[64];
  __shared__ int srank[Uc];
  int bh = blockIdx.x, tid = threadIdx.x;
  int b = bh >> 3, h = bh & 7;
  const float* m = M + bh * Lc;
  for (int e = tid; e < Lc; e += 256) {
    unsigned bb = __float_as_uint(m[e]);
    su[e] = (bb & 0x80000000u) ? ~bb : (bb | 0x80000000u);
  }
  if (tid == 0) { s_r = Uc; s_prefix = 0u; n_gt = 0; n_eq = 0; }
  __syncthreads();
  #pragma unroll
  for (int p = 0; p < 4; ++p) {
    int shift = 24 - 8 * p;
    hist[tid] = 0;
    __syncthreads();
    unsigned pref = s_prefix;
    unsigned hmask = (p == 0) ? 0u : (0xFFFFFFFFu << (shift + 8));
    for (int e = tid; e < Lc; e += 256) {
      unsigned u = su[e];
      if ((u & hmask) == pref) atomicAdd(&hist[(u >> shift) & 255u], 1);
    }
    __syncthreads();
    sfx[tid] = hist[tid];
    __syncthreads();
    for (int off = 1; off < 256; off <<= 1) {   // inclusive suffix sum
      int v = (tid + off < 256) ? sfx[tid + off] : 0;
      __syncthreads();
      sfx[tid] += v;
      __syncthreads();
    }
    int r = s_r;
    __syncthreads();                            // all read s_r before update
    int above = (tid < 255) ? sfx[tid + 1] : 0;
    if (sfx[tid] >= r && above < r) {           // unique digit
      s_r = r - above;
      s_prefix = pref | ((unsigned)tid << shift);
    }
    __syncthreads();
  }
  unsigned T = s_prefix;                        // exact 45th-largest key
  int rf = s_r;                                 // #equals to take (>=1)
  for (int e = tid; e < Lc; e += 256) {
    unsigned u = su[e];
    if (u > T) {
      int p = atomicAdd(&n_gt, 1);              // <= 44
      cu[p] = u; cidx[p] = e;
    } else if (u == T) {
      int p = atomicAdd(&n_eq, 1);
      if (p < 64) eqi[p] = e;                   // >64-way ties: impossible for random-normal M
    }
  }
  __syncthreads();
  int ne = n_eq < 64 ? n_eq : 64;
  if (tid < ne) {
    int myi = eqi[tid];
    int rank = 0;
    for (int j = 0; j < ne; ++j) rank += (eqi[j] < myi);
    if (rank < rf) {
      int p = atomicAdd(&n_gt, 1);              // completes to exactly 45
      cu[p] = T; cidx[p] = myi;
    }
  }
  __syncthreads();
  if (tid < Uc) {
    unsigned mu = cu[tid]; int mi = cidx[tid];
    int rank = 0;
    for (int j = 0; j < Uc; ++j) {
      unsigned ju = cu[j]; int ji = cidx[j];
      rank += (ju > mu) || (ju == mu && ji < mi);
    }
    topk[bh * Uc + rank] = mi;
    srank[rank] = mi;
  }
  __syncthreads();
  const float4* Q4 = (const float4*)Q;
  float4* qg4 = (float4*)qg;
  for (int e = tid; e < Uc * 16; e += 256) {    // coalesced pre-gather of selected Q rows
    int t = e >> 4, dq = e & 15;
    qg4[bh * Uc * 16 + e] = Q4[((b * Lc + srank[t]) * Hc + h) * 16 + dq];
  }
}

// Flash-decoding partials: one block per (bh, CH-key chunk), CH = 4096/NC.
// NOTE: phase 2 assumes CH == 64 (one wave per score row); the NC=64 path is
// always taken in practice (ws_size >> 14 MB).
template<int NC>
__global__ __launch_bounds__(256) void k_attn(const float* __restrict__ qg, const float* __restrict__ K,
                                              const float* __restrict__ V, const int* __restrict__ amask,
                                              float* __restrict__ pO, float* __restrict__ pM,
                                              float* __restrict__ pL) {
  constexpr int CH = Lc / NC;
  constexpr int TG = 256 / CH;
  constexpr int SCW = CH + 4;      // row stride 68 floats = 272 B (16-B aligned rows)
  int chunk = blockIdx.x, bh = blockIdx.y;
  int b = bh >> 3, h = bh & 7;
  int tid = threadIdx.x;
  __shared__ __align__(16) float qs[Uc * 64];
  __shared__ __align__(16) float sc[48][SCW];
  {
    const float4* qg4 = (const float4*)qg;
    float4* qs4w = (float4*)qs;
    for (int e = tid; e < Uc * 16; e += 256) qs4w[e] = qg4[bh * Uc * 16 + e];
  }
  for (int e = tid; e < 3 * SCW; e += 256) sc[45 + e / SCW][e % SCW] = 0.f;
  __syncthreads();
  {
    int k = tid % CH, tg = tid / CH;
    int key = chunk * CH + k;
    const float4* K4 = (const float4*)K;
    int kb = ((b * Lc + key) * Hc + h) * 16;
    float4 kr[16];
    #pragma unroll
    for (int j = 0; j < 16; ++j) kr[j] = K4[kb + j];
    int mk = amask[b * Lc + key];
    const float4* qs4 = (const float4*)qs;
    for (int t = tg; t < Uc; t += TG) {
      float a0 = 0.f, a1 = 0.f, a2 = 0.f, a3 = 0.f;   // 4 independent fmaf chains
      #pragma unroll
      for (int j = 0; j < 16; j += 4) {
        a0 = dot4_acc(qs4[t * 16 + j],     kr[j],     a0);
        a1 = dot4_acc(qs4[t * 16 + j + 1], kr[j + 1], a1);
        a2 = dot4_acc(qs4[t * 16 + j + 2], kr[j + 2], a2);
        a3 = dot4_acc(qs4[t * 16 + j + 3], kr[j + 3], a3);
      }
      float acc = (a0 + a1) + (a2 + a3);
      sc[t][k] = mk ? acc * 0.125f : -INFINITY;
    }
  }
  __syncthreads();
  {
    // CH=64: one wave per score row; DPP reductions (VALU pipe).
    int w = tid >> 6, lane = tid & 63;
    for (int t = w; t < Uc; t += 4) {
      float x = sc[t][lane];
      float ml = wave_max_bcast(x);
      float p = (ml != -INFINITY) ? __expf(x - ml) : 0.f;   // fully-masked chunk guard
      sc[t][lane] = p;
      float ls = wave_sum_bcast(p);
      if (lane == 0) {
        pM[(bh * NC + chunk) * Uc + t] = ml;
        pL[(bh * NC + chunk) * Uc + t] = ls;
      }
    }
  }
  __syncthreads();
  {
    int ty = tid >> 4, tx = tid & 15;
    float4 o0 = {0.f, 0.f, 0.f, 0.f};
    float4 o1 = {0.f, 0.f, 0.f, 0.f};
    float4 o2 = {0.f, 0.f, 0.f, 0.f};
    const float4* V4 = (const float4*)V;
    const float4* s0 = (const float4*)&sc[ty][0];        // rows 16-B aligned (SCW=68)
    const float4* s1 = (const float4*)&sc[ty + 16][0];
    const float4* s2 = (const float4*)&sc[ty + 32][0];
    int vbase = (b * Lc + chunk * CH) * (Hc * 16) + h * 16 + tx;
    #pragma unroll 2
    for (int kq = 0; kq < CH / 4; ++kq) {
      float4 p0 = s0[kq], p1 = s1[kq], p2 = s2[kq];      // 4 keys per ds_read_b128
      float4 va = V4[vbase + (4 * kq + 0) * (Hc * 16)];
      float4 vb = V4[vbase + (4 * kq + 1) * (Hc * 16)];
      float4 vc = V4[vbase + (4 * kq + 2) * (Hc * 16)];
      float4 vd = V4[vbase + (4 * kq + 3) * (Hc * 16)];
      o0.x = fmaf(p0.x, va.x, o0.x); o0.y = fmaf(p0.x, va.y, o0.y); o0.z = fmaf(p0.x, va.z, o0.z); o0.w = fmaf(p0.x, va.w, o0.w);
      o1.x = fmaf(p1.x, va.x, o1.x); o1.y = fmaf(p1.x, va.y, o1.y); o1.z = fmaf(p1.x, va.z, o1.z); o1.w = fmaf(p1.x, va.w, o1.w);
      o2.x = fmaf(p2.x, va.x, o2.x); o2.y = fmaf(p2.x, va.y, o2.y); o2.z = fmaf(p2.x, va.z, o2.z); o2.w = fmaf(p2.x, va.w, o2.w);
      o0.x = fmaf(p0.y, vb.x, o0.x); o0.y = fmaf(p0.y, vb.y, o0.y); o0.z = fmaf(p0.y, vb.z, o0.z); o0.w = fmaf(p0.y, vb.w, o0.w);
      o1.x = fmaf(p1.y, vb.x, o1.x); o1.y = fmaf(p1.y, vb.y, o1.y); o1.z = fmaf(p1.y, vb.z, o1.z); o1.w = fmaf(p1.y, vb.w, o1.w);
      o2.x = fmaf(p2.y, vb.x, o2.x); o2.y = fmaf(p2.y, vb.y, o2.y); o2.z = fmaf(p2.y, vb.z, o2.z); o2.w = fmaf(p2.y, vb.w, o2.w);
      o0.x = fmaf(p0.z, vc.x, o0.x); o0.y = fmaf(p0.z, vc.y, o0.y); o0.z = fmaf(p0.z, vc.z, o0.z); o0.w = fmaf(p0.z, vc.w, o0.w);
      o1.x = fmaf(p1.z, vc.x, o1.x); o1.y = fmaf(p1.z, vc.y, o1.y); o1.z = fmaf(p1.z, vc.z, o1.z); o1.w = fmaf(p1.z, vc.w, o1.w);
      o2.x = fmaf(p2.z, vc.x, o2.x); o2.y = fmaf(p2.z, vc.y, o2.y); o2.z = fmaf(p2.z, vc.z, o2.z); o2.w = fmaf(p2.z, vc.w, o2.w);
      o0.x = fmaf(p0.w, vd.x, o0.x); o0.y = fmaf(p0.w, vd.y, o0.y); o0.z = fmaf(p0.w, vd.z, o0.z); o0.w = fmaf(p0.w, vd.w, o0.w);
      o1.x = fmaf(p1.w, vd.x, o1.x); o1.y = fmaf(p1.w, vd.y, o1.y); o1.z = fmaf(p1.w, vd.z, o1.z); o1.w = fmaf(p1.w, vd.w, o1.w);
      o2.x = fmaf(p2.w, vd.x, o2.x); o2.y = fmaf(p2.w, vd.y, o2.y); o2.z = fmaf(p2.w, vd.z, o2.z); o2.w = fmaf(p2.w, vd.w, o2.w);
    }
    float4* pO4 = (float4*)pO;
    int obase = ((bh * NC + chunk) * Uc) * 16 + tx;
    pO4[obase + ty * 16] = o0;
    pO4[obase + (ty + 16) * 16] = o1;
    if (ty < 13) pO4[obase + (ty + 32) * 16] = o2;
  }
}

// Exact merge of chunk partials; out[b][t][h][d].
template<int NC>
__global__ __launch_bounds__(256) void k_merge(const float* __restrict__ pO, const float* __restrict__ pM,
                                               const float* __restrict__ pL, float* __restrict__ out) {
  int f = blockIdx.x * 256 + threadIdx.x;   // 180*256 == 46080
  int d = f & 63, h = (f >> 6) & 7;
  int bt = f >> 9;
  int t = bt % Uc, b = bt / Uc;
  int bh = b * 8 + h;
  float m = -INFINITY;
  for (int c = 0; c < NC; ++c) m = fmaxf(m, pM[(bh * NC + c) * Uc + t]);
  float den = 0.f, num = 0.f;
  for (int c = 0; c < NC; ++c) {
    float mc = pM[(bh * NC + c) * Uc + t];
    float wgt = (mc == -INFINITY) ? 0.f : __expf(mc - m);
    den += wgt * pL[(bh * NC + c) * Uc + t];
    num += wgt * pO[((bh * NC + c) * Uc + t) * 64 + d];
  }
  out[f] = num / den;
}

extern "C" void kernel_launch(void* const* d_in, const int* in_sizes, int n_in,
                              void* d_out, int out_size, void* d_ws, size_t ws_size,
                              hipStream_t stream) {
  const float* Q = (const float*)d_in[0];
  const float* K = (const float*)d_in[1];
  const float* V = (const float*)d_in[2];
  const int* amask = (const int*)d_in[3];
  float* out = (float*)d_out;
  char* ws = (char*)d_ws;
  float* M    = (float*)(ws + 0x000000);   // 65536 floats (256 KB)
  int*   topk = (int*)(ws + 0x040000);     // 720 ints
  float* qg   = (float*)(ws + 0x041000);   // 16*45*64 floats (184,320 B)
  unsigned* gidx = (unsigned*)(ws + 0x070000);  // 92160 u32 (368,640 B) packed u16 idx
  float* pM   = (float*)(ws + 0x130000);
  // ws_size is constant across calls -> branch is deterministic (graph-safe).
  size_t need64 = 0x130000UL + 64UL * 190080UL;   // pM+pL+pO for NC=64 (~13.4 MB)
  size_t need32 = 0x130000UL + 32UL * 190080UL;
  int NC = ws_size >= need64 ? 64 : (ws_size >= need32 ? 32 : 16);
  float* pL = pM + 16 * NC * Uc;
  float* pO = pL + 16 * NC * Uc;

  k_genidx<<<360, 256, 0, stream>>>(gidx);
  k_scoreM<<<4096, 256, 0, stream>>>(Q, K, gidx, M);
  k_topk<<<BHc, 256, 0, stream>>>(M, Q, topk, qg);
  if (NC == 64) {
    k_attn<64><<<dim3(64, BHc), 256, 0, stream>>>(qg, K, V, amask, pO, pM, pL);
    k_merge<64><<<180, 256, 0, stream>>>(pO, pM, pL, out);
  } else if (NC == 32) {
    k_attn<32><<<dim3(32, BHc), 256, 0, stream>>>(qg, K, V, amask, pO, pM, pL);
    k_merge<32><<<180, 256, 0, stream>>>(pO, pM, pL, out);
  } else {
    k_attn<16><<<dim3(16, BHc), 256, 0, stream>>>(qg, K, V, amask, pO, pM, pL);
    k_merge<16><<<180, 256, 0, stream>>>(pO, pM, pL, out);
  }
}

// Round 5
// 165.861 us; speedup vs baseline: 1.4466x; 1.1550x over previous
//
#include <hip/hip_runtime.h>
#include <math.h>

// ProbSparse attention (Informer). B=2 L=4096 H=8 D=64, U_part=u=45.
// R12: scoreM reverted to R8 exactly (in-kernel threefry). Verdict from
// R9-R11: hoisting the idx table always costs more in L2 pollution than the
// redundant hashing it saves (per-XCD set 2MB K + 2MB Q == 4MB L2; any extra
// stream evicts K -> FETCH 18->54/30MB). scoreM's ~43us sits ~5us above the
// L2 line-rate floor (38us) with the threefry mostly hidden under memory.
// New this round: k_merge re-parallelized 180x256 (0.7 blk/CU, 64 serial
// chunk-iters/thread, latency-exposed) -> 720 blocks (one per bh,t), thread
// (cg,d) covers NC/4 chunks, 2-sync LDS combine. Probe: if total drops to
// ~165-172, merge was the latency sleeper; if ~180, merge was small and the
// residual lives in k_attn/k_topk.
#define JAX_PARTITIONABLE 1

constexpr int Bc = 2, Lc = 4096, Hc = 8, Dc = 64;
constexpr int BHc = Bc * Hc;     // 16
constexpr int Uc = 45;           // top-k queries
constexpr int NSc = 45;          // samples per query

typedef float vfloat4 __attribute__((ext_vector_type(4)));

struct TF2 { unsigned a, b; };

__host__ __device__ constexpr unsigned rotl32(unsigned v, int n) {
  return (v << n) | (v >> (32 - n));
}

// Threefry-2x32, 20 rounds (JAX reference schedule).
__host__ __device__ constexpr TF2 tf2(unsigned k0, unsigned k1, unsigned x0, unsigned x1) {
  unsigned ks2 = k0 ^ k1 ^ 0x1BD11BDAu;
  x0 += k0; x1 += k1;
  x0 += x1; x1 = rotl32(x1, 13); x1 ^= x0;
  x0 += x1; x1 = rotl32(x1, 15); x1 ^= x0;
  x0 += x1; x1 = rotl32(x1, 26); x1 ^= x0;
  x0 += x1; x1 = rotl32(x1, 6);  x1 ^= x0;
  x0 += k1; x1 += ks2 + 1u;
  x0 += x1; x1 = rotl32(x1, 17); x1 ^= x0;
  x0 += x1; x1 = rotl32(x1, 29); x1 ^= x0;
  x0 += x1; x1 = rotl32(x1, 16); x1 ^= x0;
  x0 += x1; x1 = rotl32(x1, 24); x1 ^= x0;
  x0 += ks2; x1 += k0 + 2u;
  x0 += x1; x1 = rotl32(x1, 13); x1 ^= x0;
  x0 += x1; x1 = rotl32(x1, 15); x1 ^= x0;
  x0 += x1; x1 = rotl32(x1, 26); x1 ^= x0;
  x0 += x1; x1 = rotl32(x1, 6);  x1 ^= x0;
  x0 += k0; x1 += k1 + 3u;
  x0 += x1; x1 = rotl32(x1, 17); x1 ^= x0;
  x0 += x1; x1 = rotl32(x1, 29); x1 ^= x0;
  x0 += x1; x1 = rotl32(x1, 16); x1 ^= x0;
  x0 += x1; x1 = rotl32(x1, 24); x1 ^= x0;
  x0 += k1; x1 += ks2 + 4u;
  x0 += x1; x1 = rotl32(x1, 13); x1 ^= x0;
  x0 += x1; x1 = rotl32(x1, 15); x1 ^= x0;
  x0 += x1; x1 = rotl32(x1, 26); x1 ^= x0;
  x0 += x1; x1 = rotl32(x1, 6);  x1 ^= x0;
  x0 += ks2; x1 += k0 + 5u;
  return TF2{x0, x1};
}

// VALU-pipe partial-sum add via DPP (identity old=0 for invalid lanes).
template <int CTRL>
__device__ __forceinline__ float dpp_add(float x) {
  int t = __builtin_amdgcn_update_dpp(0, __float_as_int(x), CTRL, 0xF, 0xF, false);
  return x + __int_as_float(t);
}
// DPP-shifted value with own value as identity for invalid lanes (for max).
template <int CTRL>
__device__ __forceinline__ float dpp_idf(float x) {
  int t = __builtin_amdgcn_update_dpp(__float_as_int(x), __float_as_int(x), CTRL, 0xF, 0xF, false);
  return __int_as_float(t);
}
// Full-wave (64-lane) max/sum: result valid at lane 63, broadcast via readlane.
__device__ __forceinline__ float wave_max_bcast(float x) {
  x = fmaxf(x, dpp_idf<0x111>(x));   // row_shr:1
  x = fmaxf(x, dpp_idf<0x112>(x));   // row_shr:2
  x = fmaxf(x, dpp_idf<0x114>(x));   // row_shr:4
  x = fmaxf(x, dpp_idf<0x118>(x));   // row_shr:8  -> lane15 of each row = row max
  x = fmaxf(x, dpp_idf<0x142>(x));   // row_bcast:15
  x = fmaxf(x, dpp_idf<0x143>(x));   // row_bcast:31 -> lane63 = wave max
  return __int_as_float(__builtin_amdgcn_readlane(__float_as_int(x), 63));
}
__device__ __forceinline__ float wave_sum_bcast(float x) {
  x = dpp_add<0x111>(x);
  x = dpp_add<0x112>(x);
  x = dpp_add<0x114>(x);
  x = dpp_add<0x118>(x);
  x = dpp_add<0x142>(x);
  x = dpp_add<0x143>(x);
  return __int_as_float(__builtin_amdgcn_readlane(__float_as_int(x), 63));
}

// fmaf chain for a float4 dot accumulated into a: 4 VALU insts.
__device__ __forceinline__ float dot4_acc(float4 q, float4 k, float a) {
  a = fmaf(q.x, k.x, a);
  a = fmaf(q.y, k.y, a);
  a = fmaf(q.z, k.z, a);
  a = fmaf(q.w, k.w, a);
  return a;
}

// M[bh][q] = max_s dot(Q[q],K[idx[q][s]]) - sum_s(...)/4096.
// bh = blockIdx&15: with round-robin block->XCD dispatch, each XCD sees 2 bh
// -> 2 MB K slices stay L2-resident. At the L2 random-line-rate roofline
// (1.47M 64-B lines/XCD @ ~16 lines/cy ~= 38 us). Threefry stays in-kernel:
// hoisting it (R9-R11) always lost more to L2 pollution than it saved.
__global__ __launch_bounds__(256) void k_scoreM(const float* __restrict__ Q, const float* __restrict__ K,
                                                float* __restrict__ M) {
  __shared__ int sidx[720];
  int tid = threadIdx.x;
  int bx = blockIdx.x;
  int bh = bx & 15;
  int qblk = bx >> 4;              // 0..255
  int b = bh >> 3, h = bh & 7;
  int lane16 = tid & 15, qloc = tid >> 4;
  int q = qblk * 16 + qloc;
  constexpr TF2 kb = tf2(0u, 1u, 0u, 1u);
  for (int e = tid; e < 720; e += 256) {
    TF2 r = tf2(kb.a, kb.b, 0u, (unsigned)(qblk * 720 + e));
    sidx[e] = (int)((r.a ^ r.b) & 4095u);
  }
  __syncthreads();
  const vfloat4* Q4 = (const vfloat4*)Q;
  const vfloat4* K4 = (const vfloat4*)K;
  vfloat4 qr = Q4[((b * Lc + q) * Hc + h) * 16 + lane16];
  int kbase = (b * Lc * Hc + h) * 16 + lane16;
  const int* ip = sidx + qloc * NSc;
  float mx = -INFINITY, sm = 0.f;
  #pragma unroll
  for (int s0 = 0; s0 < NSc; s0 += 5) {      // 5-deep load batch: L2 loads in flight
    int kk[5];
    #pragma unroll
    for (int i = 0; i < 5; ++i) kk[i] = ip[s0 + i];
    vfloat4 kv[5];
    #pragma unroll
    for (int i = 0; i < 5; ++i) kv[i] = __builtin_nontemporal_load(&K4[kbase + kk[i] * (Hc * 16)]);
    #pragma unroll
    for (int i = 0; i < 5; ++i) {
      float p = fmaf(qr[0], kv[i][0], fmaf(qr[1], kv[i][1], fmaf(qr[2], kv[i][2], qr[3] * kv[i][3])));
      p = dpp_add<0x111>(p);                 // row_shr cascade -> lane15 = full dot
      p = dpp_add<0x112>(p);
      p = dpp_add<0x114>(p);
      p = dpp_add<0x118>(p);
      mx = fmaxf(mx, p);                     // valid at lane15; junk elsewhere (never read)
      sm += p;
    }
  }
  if (lane16 == 15) M[bh * Lc + q] = mx - sm * (1.0f / Lc);
}

// Radix-select top-45 of 4096 per bh (exact lax.top_k: value desc, index asc
// on ties). Then pre-gather the 45 selected Q rows into qg[bh][45][64].
__global__ __launch_bounds__(256) void k_topk(const float* __restrict__ M, const float* __restrict__ Q,
                                              int* __restrict__ topk, float* __restrict__ qg) {
  __shared__ unsigned su[Lc];      // 16 KB mapped keys
  __shared__ int hist[256];
  __shared__ int sfx[257];
  __shared__ unsigned s_prefix;
  __shared__ int s_r;
  __shared__ int n_gt, n_eq;
  __shared__ unsigned cu[64];
  __shared__ int cidx[64];
  __shared__ int eqi[64];
  __shared__ int srank[Uc];
  int bh = blockIdx.x, tid = threadIdx.x;
  int b = bh >> 3, h = bh & 7;
  const float* m = M + bh * Lc;
  for (int e = tid; e < Lc; e += 256) {
    unsigned bb = __float_as_uint(m[e]);
    su[e] = (bb & 0x80000000u) ? ~bb : (bb | 0x80000000u);
  }
  if (tid == 0) { s_r = Uc; s_prefix = 0u; n_gt = 0; n_eq = 0; }
  __syncthreads();
  #pragma unroll
  for (int p = 0; p < 4; ++p) {
    int shift = 24 - 8 * p;
    hist[tid] = 0;
    __syncthreads();
    unsigned pref = s_prefix;
    unsigned hmask = (p == 0) ? 0u : (0xFFFFFFFFu << (shift + 8));
    for (int e = tid; e < Lc; e += 256) {
      unsigned u = su[e];
      if ((u & hmask) == pref) atomicAdd(&hist[(u >> shift) & 255u], 1);
    }
    __syncthreads();
    sfx[tid] = hist[tid];
    __syncthreads();
    for (int off = 1; off < 256; off <<= 1) {   // inclusive suffix sum
      int v = (tid + off < 256) ? sfx[tid + off] : 0;
      __syncthreads();
      sfx[tid] += v;
      __syncthreads();
    }
    int r = s_r;
    __syncthreads();                            // all read s_r before update
    int above = (tid < 255) ? sfx[tid + 1] : 0;
    if (sfx[tid] >= r && above < r) {           // unique digit
      s_r = r - above;
      s_prefix = pref | ((unsigned)tid << shift);
    }
    __syncthreads();
  }
  unsigned T = s_prefix;                        // exact 45th-largest key
  int rf = s_r;                                 // #equals to take (>=1)
  for (int e = tid; e < Lc; e += 256) {
    unsigned u = su[e];
    if (u > T) {
      int p = atomicAdd(&n_gt, 1);              // <= 44
      cu[p] = u; cidx[p] = e;
    } else if (u == T) {
      int p = atomicAdd(&n_eq, 1);
      if (p < 64) eqi[p] = e;                   // >64-way ties: impossible for random-normal M
    }
  }
  __syncthreads();
  int ne = n_eq < 64 ? n_eq : 64;
  if (tid < ne) {
    int myi = eqi[tid];
    int rank = 0;
    for (int j = 0; j < ne; ++j) rank += (eqi[j] < myi);
    if (rank < rf) {
      int p = atomicAdd(&n_gt, 1);              // completes to exactly 45
      cu[p] = T; cidx[p] = myi;
    }
  }
  __syncthreads();
  if (tid < Uc) {
    unsigned mu = cu[tid]; int mi = cidx[tid];
    int rank = 0;
    for (int j = 0; j < Uc; ++j) {
      unsigned ju = cu[j]; int ji = cidx[j];
      rank += (ju > mu) || (ju == mu && ji < mi);
    }
    topk[bh * Uc + rank] = mi;
    srank[rank] = mi;
  }
  __syncthreads();
  const float4* Q4 = (const float4*)Q;
  float4* qg4 = (float4*)qg;
  for (int e = tid; e < Uc * 16; e += 256) {    // coalesced pre-gather of selected Q rows
    int t = e >> 4, dq = e & 15;
    qg4[bh * Uc * 16 + e] = Q4[((b * Lc + srank[t]) * Hc + h) * 16 + dq];
  }
}

// Flash-decoding partials: one block per (bh, CH-key chunk), CH = 4096/NC.
// NOTE: phase 2 assumes CH == 64 (one wave per score row); the NC=64 path is
// always taken in practice (ws_size >> 13 MB).
template<int NC>
__global__ __launch_bounds__(256) void k_attn(const float* __restrict__ qg, const float* __restrict__ K,
                                              const float* __restrict__ V, const int* __restrict__ amask,
                                              float* __restrict__ pO, float* __restrict__ pM,
                                              float* __restrict__ pL) {
  constexpr int CH = Lc / NC;
  constexpr int TG = 256 / CH;
  constexpr int SCW = CH + 4;      // row stride 68 floats = 272 B (16-B aligned rows)
  int chunk = blockIdx.x, bh = blockIdx.y;
  int b = bh >> 3, h = bh & 7;
  int tid = threadIdx.x;
  __shared__ __align__(16) float qs[Uc * 64];
  __shared__ __align__(16) float sc[48][SCW];
  {
    const float4* qg4 = (const float4*)qg;
    float4* qs4w = (float4*)qs;
    for (int e = tid; e < Uc * 16; e += 256) qs4w[e] = qg4[bh * Uc * 16 + e];
  }
  for (int e = tid; e < 3 * SCW; e += 256) sc[45 + e / SCW][e % SCW] = 0.f;
  __syncthreads();
  {
    int k = tid % CH, tg = tid / CH;
    int key = chunk * CH + k;
    const float4* K4 = (const float4*)K;
    int kb = ((b * Lc + key) * Hc + h) * 16;
    float4 kr[16];
    #pragma unroll
    for (int j = 0; j < 16; ++j) kr[j] = K4[kb + j];
    int mk = amask[b * Lc + key];
    const float4* qs4 = (const float4*)qs;
    for (int t = tg; t < Uc; t += TG) {
      float a0 = 0.f, a1 = 0.f, a2 = 0.f, a3 = 0.f;   // 4 independent fmaf chains
      #pragma unroll
      for (int j = 0; j < 16; j += 4) {
        a0 = dot4_acc(qs4[t * 16 + j],     kr[j],     a0);
        a1 = dot4_acc(qs4[t * 16 + j + 1], kr[j + 1], a1);
        a2 = dot4_acc(qs4[t * 16 + j + 2], kr[j + 2], a2);
        a3 = dot4_acc(qs4[t * 16 + j + 3], kr[j + 3], a3);
      }
      float acc = (a0 + a1) + (a2 + a3);
      sc[t][k] = mk ? acc * 0.125f : -INFINITY;
    }
  }
  __syncthreads();
  {
    // CH=64: one wave per score row; DPP reductions (VALU pipe).
    int w = tid >> 6, lane = tid & 63;
    for (int t = w; t < Uc; t += 4) {
      float x = sc[t][lane];
      float ml = wave_max_bcast(x);
      float p = (ml != -INFINITY) ? __expf(x - ml) : 0.f;   // fully-masked chunk guard
      sc[t][lane] = p;
      float ls = wave_sum_bcast(p);
      if (lane == 0) {
        pM[(bh * NC + chunk) * Uc + t] = ml;
        pL[(bh * NC + chunk) * Uc + t] = ls;
      }
    }
  }
  __syncthreads();
  {
    int ty = tid >> 4, tx = tid & 15;
    float4 o0 = {0.f, 0.f, 0.f, 0.f};
    float4 o1 = {0.f, 0.f, 0.f, 0.f};
    float4 o2 = {0.f, 0.f, 0.f, 0.f};
    const float4* V4 = (const float4*)V;
    const float4* s0 = (const float4*)&sc[ty][0];        // rows 16-B aligned (SCW=68)
    const float4* s1 = (const float4*)&sc[ty + 16][0];
    const float4* s2 = (const float4*)&sc[ty + 32][0];
    int vbase = (b * Lc + chunk * CH) * (Hc * 16) + h * 16 + tx;
    #pragma unroll 2
    for (int kq = 0; kq < CH / 4; ++kq) {
      float4 p0 = s0[kq], p1 = s1[kq], p2 = s2[kq];      // 4 keys per ds_read_b128
      float4 va = V4[vbase + (4 * kq + 0) * (Hc * 16)];
      float4 vb = V4[vbase + (4 * kq + 1) * (Hc * 16)];
      float4 vc = V4[vbase + (4 * kq + 2) * (Hc * 16)];
      float4 vd = V4[vbase + (4 * kq + 3) * (Hc * 16)];
      o0.x = fmaf(p0.x, va.x, o0.x); o0.y = fmaf(p0.x, va.y, o0.y); o0.z = fmaf(p0.x, va.z, o0.z); o0.w = fmaf(p0.x, va.w, o0.w);
      o1.x = fmaf(p1.x, va.x, o1.x); o1.y = fmaf(p1.x, va.y, o1.y); o1.z = fmaf(p1.x, va.z, o1.z); o1.w = fmaf(p1.x, va.w, o1.w);
      o2.x = fmaf(p2.x, va.x, o2.x); o2.y = fmaf(p2.x, va.y, o2.y); o2.z = fmaf(p2.x, va.z, o2.z); o2.w = fmaf(p2.x, va.w, o2.w);
      o0.x = fmaf(p0.y, vb.x, o0.x); o0.y = fmaf(p0.y, vb.y, o0.y); o0.z = fmaf(p0.y, vb.z, o0.z); o0.w = fmaf(p0.y, vb.w, o0.w);
      o1.x = fmaf(p1.y, vb.x, o1.x); o1.y = fmaf(p1.y, vb.y, o1.y); o1.z = fmaf(p1.y, vb.z, o1.z); o1.w = fmaf(p1.y, vb.w, o1.w);
      o2.x = fmaf(p2.y, vb.x, o2.x); o2.y = fmaf(p2.y, vb.y, o2.y); o2.z = fmaf(p2.y, vb.z, o2.z); o2.w = fmaf(p2.y, vb.w, o2.w);
      o0.x = fmaf(p0.z, vc.x, o0.x); o0.y = fmaf(p0.z, vc.y, o0.y); o0.z = fmaf(p0.z, vc.z, o0.z); o0.w = fmaf(p0.z, vc.w, o0.w);
      o1.x = fmaf(p1.z, vc.x, o1.x); o1.y = fmaf(p1.z, vc.y, o1.y); o1.z = fmaf(p1.z, vc.z, o1.z); o1.w = fmaf(p1.z, vc.w, o1.w);
      o2.x = fmaf(p2.z, vc.x, o2.x); o2.y = fmaf(p2.z, vc.y, o2.y); o2.z = fmaf(p2.z, vc.z, o2.z); o2.w = fmaf(p2.z, vc.w, o2.w);
      o0.x = fmaf(p0.w, vd.x, o0.x); o0.y = fmaf(p0.w, vd.y, o0.y); o0.z = fmaf(p0.w, vd.z, o0.z); o0.w = fmaf(p0.w, vd.w, o0.w);
      o1.x = fmaf(p1.w, vd.x, o1.x); o1.y = fmaf(p1.w, vd.y, o1.y); o1.z = fmaf(p1.w, vd.z, o1.z); o1.w = fmaf(p1.w, vd.w, o1.w);
      o2.x = fmaf(p2.w, vd.x, o2.x); o2.y = fmaf(p2.w, vd.y, o2.y); o2.z = fmaf(p2.w, vd.z, o2.z); o2.w = fmaf(p2.w, vd.w, o2.w);
    }
    float4* pO4 = (float4*)pO;
    int obase = ((bh * NC + chunk) * Uc) * 16 + tx;
    pO4[obase + ty * 16] = o0;
    pO4[obase + (ty + 16) * 16] = o1;
    if (ty < 13) pO4[obase + (ty + 32) * 16] = o2;
  }
}

// Exact merge of chunk partials; out[b][t][h][d].
// R12: one block per (bh,t) = 720 blocks (was 180 with 64 serial chunk-iters
// per thread, 0.7 blocks/CU -> latency-exposed). Thread (cg,d): cg=tid>>6
// covers NC/4 chunks, d=tid&63 one output dim. pM/pL reads are wave-uniform
// (broadcast); pO reads coalesced 256B per chunk. 2 syncthreads, LDS combine.
template<int NC>
__global__ __launch_bounds__(256) void k_merge(const float* __restrict__ pO, const float* __restrict__ pM,
                                               const float* __restrict__ pL, float* __restrict__ out) {
  constexpr int CPT = NC / 4;          // chunks per thread-group
  __shared__ float smax[4];
  __shared__ float sden[4];
  __shared__ float snum[4][64];
  int bid = blockIdx.x;                // 720 = 45*16, bid = t*16 + bh
  int bh = bid & 15, t = bid >> 4;
  int b = bh >> 3, h = bh & 7;
  int tid = threadIdx.x;
  int d = tid & 63, cg = tid >> 6;
  int mlbase = bh * NC * Uc + t;       // pM/pL index: + c*Uc
  float lm = -INFINITY;
  #pragma unroll 4
  for (int c = cg * CPT; c < (cg + 1) * CPT; ++c)
    lm = fmaxf(lm, pM[mlbase + c * Uc]);
  if (d == 0) smax[cg] = lm;
  __syncthreads();
  float m = fmaxf(fmaxf(smax[0], smax[1]), fmaxf(smax[2], smax[3]));
  float den = 0.f, num = 0.f;
  #pragma unroll 4
  for (int c = cg * CPT; c < (cg + 1) * CPT; ++c) {
    float mc = pM[mlbase + c * Uc];
    float wgt = (mc == -INFINITY) ? 0.f : __expf(mc - m);
    den += wgt * pL[mlbase + c * Uc];
    num += wgt * pO[(mlbase + c * Uc) * 64 + d];
  }
  if (d == 0) sden[cg] = den;
  snum[cg][d] = num;
  __syncthreads();
  if (cg == 0) {
    float dn = sden[0] + sden[1] + sden[2] + sden[3];
    float nm = snum[0][d] + snum[1][d] + snum[2][d] + snum[3][d];
    out[((b * Uc + t) * Hc + h) * 64 + d] = nm / dn;
  }
}

extern "C" void kernel_launch(void* const* d_in, const int* in_sizes, int n_in,
                              void* d_out, int out_size, void* d_ws, size_t ws_size,
                              hipStream_t stream) {
  const float* Q = (const float*)d_in[0];
  const float* K = (const float*)d_in[1];
  const float* V = (const float*)d_in[2];
  const int* amask = (const int*)d_in[3];
  float* out = (float*)d_out;
  char* ws = (char*)d_ws;
  float* M    = (float*)(ws + 0x000000);   // 65536 floats (256 KB)
  int*   topk = (int*)(ws + 0x040000);     // 720 ints
  float* qg   = (float*)(ws + 0x041000);   // 16*45*64 floats (184,320 B)
  float* pM   = (float*)(ws + 0x070000);
  // ws_size is constant across calls -> branch is deterministic (graph-safe).
  size_t need64 = 0x70000UL + 64UL * 190080UL;   // pM+pL+pO for NC=64 (~12.6 MB)
  size_t need32 = 0x70000UL + 32UL * 190080UL;
  int NC = ws_size >= need64 ? 64 : (ws_size >= need32 ? 32 : 16);
  float* pL = pM + 16 * NC * Uc;
  float* pO = pL + 16 * NC * Uc;

  k_scoreM<<<4096, 256, 0, stream>>>(Q, K, M);
  k_topk<<<BHc, 256, 0, stream>>>(M, Q, topk, qg);
  if (NC == 64) {
    k_attn<64><<<dim3(64, BHc), 256, 0, stream>>>(qg, K, V, amask, pO, pM, pL);
    k_merge<64><<<BHc * Uc, 256, 0, stream>>>(pO, pM, pL, out);
  } else if (NC == 32) {
    k_attn<32><<<dim3(32, BHc), 256, 0, stream>>>(qg, K, V, amask, pO, pM, pL);
    k_merge<32><<<BHc * Uc, 256, 0, stream>>>(pO, pM, pL, out);
  } else {
    k_attn<16><<<dim3(16, BHc), 256, 0, stream>>>(qg, K, V, amask, pO, pM, pL);
    k_merge<16><<<BHc * Uc, 256, 0, stream>>>(pO, pM, pL, out);
  }
}